// Round 1
// baseline (1269.836 us; speedup 1.0000x reference)
//
#include <hip/hip_runtime.h>
#include <math.h>

// Problem constants (from reference)
#define N_ROWS  500000
#define DIM     128
#define NNZ     262144
#define LR      0.001f
#define B1      0.9f
#define B2      0.999f
#define EPS     1e-8f

// float4 elements per row (128 floats / 4)
#define Q_PER_ROW   (DIM / 4)          // 32
#define TOTAL_Q     (N_ROWS * Q_PER_ROW) // 16,000,000

// ---------------------------------------------------------------------------
// Kernel 1: scatter inverse map  inv[idx[i]] = i   (inv pre-set to -1 via
// hipMemsetAsync 0xFF)
// ---------------------------------------------------------------------------
__global__ __launch_bounds__(256) void build_inv_kernel(
    const int* __restrict__ idx, int* __restrict__ inv)
{
    int i = blockIdx.x * blockDim.x + threadIdx.x;
    if (i < NNZ) {
        inv[idx[i]] = i;
    }
}

// ---------------------------------------------------------------------------
// Kernel 2: fused copy + sparse Adam update, one thread per float4.
// Outputs: out[0 .. 64M)   = param_new
//          out[64M .. 128M)= m_new
//          out[128M..192M) = v_new
// ---------------------------------------------------------------------------
__global__ __launch_bounds__(256) void adam_fused_kernel(
    const float4* __restrict__ param,
    const float4* __restrict__ m,
    const float4* __restrict__ v,
    const float4* __restrict__ grad,
    const int*    __restrict__ inv,
    float4* __restrict__ out,
    float lr_t, float bc1, float bc2)
{
    const int tid = blockIdx.x * blockDim.x + threadIdx.x;
    if (tid >= TOTAL_Q) return;

    const int row  = tid >> 5;   // tid / 32
    const int quad = tid & 31;   // tid % 32

    float4 p  = param[tid];
    float4 mm = m[tid];
    float4 vv = v[tid];

    const int j = inv[row];      // wave-broadcast (same for 32 lanes)

    if (j >= 0) {
        float4 g = grad[j * Q_PER_ROW + quad];

        // m_new = m + (1-b1)*(g - m)
        mm.x += (1.0f - B1) * (g.x - mm.x);
        mm.y += (1.0f - B1) * (g.y - mm.y);
        mm.z += (1.0f - B1) * (g.z - mm.z);
        mm.w += (1.0f - B1) * (g.w - mm.w);

        // v_new = v + (1-b2)*(g*g - v)
        vv.x += (1.0f - B2) * (g.x * g.x - vv.x);
        vv.y += (1.0f - B2) * (g.y * g.y - vv.y);
        vv.z += (1.0f - B2) * (g.z * g.z - vv.z);
        vv.w += (1.0f - B2) * (g.w * g.w - vv.w);

        // hats + param update
        float mtx = mm.x / bc1, mty = mm.y / bc1, mtz = mm.z / bc1, mtw = mm.w / bc1;
        float vtx = vv.x / bc2, vty = vv.y / bc2, vtz = vv.z / bc2, vtw = vv.w / bc2;

        p.x -= lr_t * mtx / (sqrtf(vtx) + EPS);
        p.y -= lr_t * mty / (sqrtf(vty) + EPS);
        p.z -= lr_t * mtz / (sqrtf(vtz) + EPS);
        p.w -= lr_t * mtw / (sqrtf(vtw) + EPS);
    }

    out[tid]               = p;   // param_new
    out[tid + TOTAL_Q]     = mm;  // m_new
    out[tid + 2 * TOTAL_Q] = vv;  // v_new
}

// ---------------------------------------------------------------------------
extern "C" void kernel_launch(void* const* d_in, const int* in_sizes, int n_in,
                              void* d_out, int out_size, void* d_ws, size_t ws_size,
                              hipStream_t stream)
{
    const float* param = (const float*)d_in[0];
    const float* m     = (const float*)d_in[1];
    const float* v     = (const float*)d_in[2];
    const float* grad  = (const float*)d_in[3];
    const int*   idx   = (const int*)d_in[4];

    int* inv = (int*)d_ws; // N_ROWS ints = 2 MB

    // Bias-correction scalars (ITERATION = 1), computed in double then
    // narrowed to fp32 exactly like jax does.
    double bc1d = 1.0 - (double)0.9;    // 0.1
    double bc2d = 1.0 - (double)0.999;  // 0.001
    float bc1 = (float)bc1d;
    float bc2 = (float)bc2d;
    float lr_t = LR * sqrtf(bc2) / bc1;

    // inv = -1 everywhere (0xFFFFFFFF)
    hipMemsetAsync(inv, 0xFF, (size_t)N_ROWS * sizeof(int), stream);

    // scatter inverse index map
    build_inv_kernel<<<(NNZ + 255) / 256, 256, 0, stream>>>(idx, inv);

    // fused copy + adam
    const int total = TOTAL_Q;
    adam_fused_kernel<<<(total + 255) / 256, 256, 0, stream>>>(
        (const float4*)param, (const float4*)m, (const float4*)v,
        (const float4*)grad, inv, (float4*)d_out, lr_t, bc1, bc2);
}